// Round 1
// baseline (526.011 us; speedup 1.0000x reference)
//
#include <hip/hip_runtime.h>

namespace {
constexpr int T = 512;
constexpr int BATCH = 512;
constexpr int D = 32;
constexpr int H = 64;
constexpr int G = 3 * H; // 192
}

__device__ __forceinline__ float fast_sigmoid(float x) {
    return 1.0f / (1.0f + __expf(-x));
}
__device__ __forceinline__ float fast_tanh(float x) {
    // 1 - 2/(e^{2x}+1); saturates correctly via inf/0 at extremes
    return 1.0f - 2.0f / (__expf(2.0f * x) + 1.0f);
}

__global__ __launch_bounds__(G) void gru_fused_kernel(
    const float* __restrict__ x,
    const float* __restrict__ w_ih_f, const float* __restrict__ w_hh_f,
    const float* __restrict__ b_ih_f, const float* __restrict__ b_hh_f,
    const float* __restrict__ w_ih_b, const float* __restrict__ b_ih_b,
    const float* __restrict__ b_hh_b,
    const float* __restrict__ fc1_w, const float* __restrict__ fc1_b,
    const float* __restrict__ fc2_w, const float* __restrict__ fc2_b,
    float* __restrict__ out)
{
    const int b    = blockIdx.x;      // batch row
    const int g    = threadIdx.x;     // 0..191 gate-output index
    const int wave = g >> 6;          // 0 = r, 1 = z, 2 = n
    const int j    = g & 63;          // hidden index within gate

    __shared__ float h_lds[H];
    __shared__ float rz_lds[2 * H];
    __shared__ float last_lds[2 * H];

    // ---- per-thread weight rows in registers ----
    float wih[D];
    {
        const float4* p = reinterpret_cast<const float4*>(w_ih_f + g * D);
        #pragma unroll
        for (int k4 = 0; k4 < D / 4; ++k4) {
            float4 v = p[k4];
            wih[4 * k4 + 0] = v.x; wih[4 * k4 + 1] = v.y;
            wih[4 * k4 + 2] = v.z; wih[4 * k4 + 3] = v.w;
        }
    }
    float whh[H];
    {
        const float4* p = reinterpret_cast<const float4*>(w_hh_f + g * H);
        #pragma unroll
        for (int k4 = 0; k4 < H / 4; ++k4) {
            float4 v = p[k4];
            whh[4 * k4 + 0] = v.x; whh[4 * k4 + 1] = v.y;
            whh[4 * k4 + 2] = v.z; whh[4 * k4 + 3] = v.w;
        }
    }

    const float bias_ih = b_ih_f[g];
    const float bias_hh = b_hh_f[g];
    // r/z: sigmoid(xdot + b_ih + hdot + b_hh)  -> fold both biases
    // n  : tanh((xdot + b_ih) + r*(hdot + b_hh)) -> only b_ih folded
    const float bias_pre = (wave == 2) ? bias_ih : (bias_ih + bias_hh);

    if (g < H) h_lds[g] = 0.0f;
    __syncthreads();

    const float* xrow = x + (size_t)b * T * D;

    for (int t = 0; t < T; ++t) {
        const float* xt = xrow + t * D;   // uniform address -> scalar loads

        // h-dot first (independent of x loads; gives loads time to land)
        float hd0 = 0.f, hd1 = 0.f, hd2 = 0.f, hd3 = 0.f;
        const float4* h4 = reinterpret_cast<const float4*>(h_lds);
        #pragma unroll
        for (int k4 = 0; k4 < H / 4; ++k4) {
            float4 hv = h4[k4];            // uniform LDS broadcast
            hd0 = fmaf(whh[4 * k4 + 0], hv.x, hd0);
            hd1 = fmaf(whh[4 * k4 + 1], hv.y, hd1);
            hd2 = fmaf(whh[4 * k4 + 2], hv.z, hd2);
            hd3 = fmaf(whh[4 * k4 + 3], hv.w, hd3);
        }
        const float hdot = (hd0 + hd1) + (hd2 + hd3);

        float xd = bias_pre;
        #pragma unroll
        for (int k = 0; k < D; ++k) xd = fmaf(wih[k], xt[k], xd);

        if (wave < 2) {
            rz_lds[wave * H + j] = fast_sigmoid(xd + hdot);
        }
        __syncthreads();   // r,z visible; all h-dots complete
        if (wave == 2) {
            const float r    = rz_lds[j];
            const float z    = rz_lds[H + j];
            const float hold = h_lds[j];
            const float n    = fast_tanh(xd + r * (hdot + bias_hh));
            h_lds[j] = (1.0f - z) * n + z * hold;
        }
        __syncthreads();   // h updated before next step reads it
    }

    // ---- epilogue ----
    // forward final state
    if (wave == 0) last_lds[j] = h_lds[j];

    // backward direction: exactly ONE step from h0 = 0 on x[b][T-1][:]
    if (wave == 2) {
        const float* xT = xrow + (T - 1) * D;  // uniform
        float xr = b_ih_b[j];
        float xz = b_ih_b[H + j];
        float xn = b_ih_b[2 * H + j];
        #pragma unroll
        for (int k = 0; k < D; ++k) {
            const float xv = xT[k];
            xr = fmaf(w_ih_b[(size_t)j * D + k],           xv, xr);
            xz = fmaf(w_ih_b[(size_t)(H + j) * D + k],     xv, xz);
            xn = fmaf(w_ih_b[(size_t)(2 * H + j) * D + k], xv, xn);
        }
        const float r = fast_sigmoid(xr + b_hh_b[j]);
        const float z = fast_sigmoid(xz + b_hh_b[H + j]);
        const float n = fast_tanh(xn + r * b_hh_b[2 * H + j]);
        last_lds[H + j] = (1.0f - z) * n;   // z*h0 = 0
    }
    __syncthreads();

    // head: h1 = leaky(fc1_w @ last + fc1_b); out = fc2_w @ h1 + fc2_b
    if (wave == 0) {
        float acc = fc1_b[j];
        const float* w1 = fc1_w + (size_t)j * (2 * H);
        #pragma unroll 8
        for (int c = 0; c < 2 * H; ++c) acc = fmaf(w1[c], last_lds[c], acc);
        acc = (acc >= 0.0f) ? acc : 0.2f * acc;
        float red = acc * fc2_w[j];
        #pragma unroll
        for (int off = 32; off > 0; off >>= 1)
            red += __shfl_down(red, off);
        if (j == 0) out[b] = red + fc2_b[0];
    }
}

extern "C" void kernel_launch(void* const* d_in, const int* in_sizes, int n_in,
                              void* d_out, int out_size, void* d_ws, size_t ws_size,
                              hipStream_t stream) {
    const float* x      = (const float*)d_in[0];
    const float* w_ih_f = (const float*)d_in[1];
    const float* w_hh_f = (const float*)d_in[2];
    const float* b_ih_f = (const float*)d_in[3];
    const float* b_hh_f = (const float*)d_in[4];
    const float* w_ih_b = (const float*)d_in[5];
    // d_in[6] = w_hh_b: unused (backward direction runs exactly one step from h0=0)
    const float* b_ih_b = (const float*)d_in[7];
    const float* b_hh_b = (const float*)d_in[8];
    const float* fc1_w  = (const float*)d_in[9];
    const float* fc1_b  = (const float*)d_in[10];
    const float* fc2_w  = (const float*)d_in[11];
    const float* fc2_b  = (const float*)d_in[12];
    float* out = (float*)d_out;

    gru_fused_kernel<<<BATCH, G, 0, stream>>>(
        x, w_ih_f, w_hh_f, b_ih_f, b_hh_f,
        w_ih_b, b_ih_b, b_hh_b,
        fc1_w, fc1_b, fc2_w, fc2_b, out);
}

// Round 2
// 326.008 us; speedup vs baseline: 1.6135x; 1.6135x over previous
//
#include <hip/hip_runtime.h>

namespace {
constexpr int T = 512;
constexpr int BATCH = 512;
constexpr int D = 32;
constexpr int H = 64;
constexpr int G = 3 * H; // 192
}

__device__ __forceinline__ float fast_sigmoid(float x) {
    return 1.0f / (1.0f + __expf(-x));
}
__device__ __forceinline__ float fast_tanh(float x) {
    // 1 - 2/(e^{2x}+1); saturates correctly via inf/0 at extremes
    return 1.0f - 2.0f / (__expf(2.0f * x) + 1.0f);
}

__global__ __launch_bounds__(G) void gru_fused_kernel(
    const float* __restrict__ x,
    const float* __restrict__ w_ih_f, const float* __restrict__ w_hh_f,
    const float* __restrict__ b_ih_f, const float* __restrict__ b_hh_f,
    const float* __restrict__ w_ih_b, const float* __restrict__ b_ih_b,
    const float* __restrict__ b_hh_b,
    const float* __restrict__ fc1_w, const float* __restrict__ fc1_b,
    const float* __restrict__ fc2_w, const float* __restrict__ fc2_b,
    float* __restrict__ out)
{
    const int b    = blockIdx.x;      // batch row
    const int g    = threadIdx.x;     // 0..191 gate-output index
    const int wave = g >> 6;          // 0 = r, 1 = z, 2 = n
    const int j    = g & 63;          // hidden index within gate

    // x row staged in LDS: removes per-step HBM-latency from the recurrence
    __shared__ float4 x_lds[T * D / 4];          // 64 KB
    __shared__ float4 h_lds4[H / 4];             // h as float4 for broadcast reads
    __shared__ float  rz_lds[2 * H];
    __shared__ float  last_lds[2 * H];

    // ---- per-thread weight rows in registers ----
    float wih[D];
    {
        const float4* p = reinterpret_cast<const float4*>(w_ih_f + g * D);
        #pragma unroll
        for (int k4 = 0; k4 < D / 4; ++k4) {
            float4 v = p[k4];
            wih[4 * k4 + 0] = v.x; wih[4 * k4 + 1] = v.y;
            wih[4 * k4 + 2] = v.z; wih[4 * k4 + 3] = v.w;
        }
    }
    float whh[H];
    {
        const float4* p = reinterpret_cast<const float4*>(w_hh_f + g * H);
        #pragma unroll
        for (int k4 = 0; k4 < H / 4; ++k4) {
            float4 v = p[k4];
            whh[4 * k4 + 0] = v.x; whh[4 * k4 + 1] = v.y;
            whh[4 * k4 + 2] = v.z; whh[4 * k4 + 3] = v.w;
        }
    }

    const float bias_ih = b_ih_f[g];
    const float bias_hh = b_hh_f[g];
    // r/z: sigmoid(xdot + b_ih + hdot + b_hh)  -> fold both biases
    // n  : tanh((xdot + b_ih) + r*(hdot + b_hh)) -> only b_ih folded
    const float bias_pre = (wave == 2) ? bias_ih : (bias_ih + bias_hh);

    // ---- stage x row into LDS (coalesced float4) ----
    {
        const float4* xg = reinterpret_cast<const float4*>(x + (size_t)b * T * D);
        #pragma unroll 4
        for (int i = g; i < T * D / 4; i += G) x_lds[i] = xg[i];
    }
    if (g < H / 4) h_lds4[g] = make_float4(0.f, 0.f, 0.f, 0.f);
    __syncthreads();

    float* h_lds = reinterpret_cast<float*>(h_lds4);

    for (int t = 0; t < T; ++t) {
        // h-dot: 8 accumulator chains (8-deep) over LDS broadcast reads
        float hd0 = 0.f, hd1 = 0.f, hd2 = 0.f, hd3 = 0.f;
        float hd4 = 0.f, hd5 = 0.f, hd6 = 0.f, hd7 = 0.f;
        #pragma unroll
        for (int k8 = 0; k8 < H / 8; ++k8) {
            float4 ha = h_lds4[2 * k8];
            float4 hb = h_lds4[2 * k8 + 1];
            hd0 = fmaf(whh[8 * k8 + 0], ha.x, hd0);
            hd1 = fmaf(whh[8 * k8 + 1], ha.y, hd1);
            hd2 = fmaf(whh[8 * k8 + 2], ha.z, hd2);
            hd3 = fmaf(whh[8 * k8 + 3], ha.w, hd3);
            hd4 = fmaf(whh[8 * k8 + 4], hb.x, hd4);
            hd5 = fmaf(whh[8 * k8 + 5], hb.y, hd5);
            hd6 = fmaf(whh[8 * k8 + 6], hb.z, hd6);
            hd7 = fmaf(whh[8 * k8 + 7], hb.w, hd7);
        }
        const float hdot = ((hd0 + hd1) + (hd2 + hd3)) + ((hd4 + hd5) + (hd6 + hd7));

        // x-dot: 4 accumulator chains from LDS broadcast
        float xa = bias_pre, xb2 = 0.f, xc = 0.f, xd4 = 0.f;
        const float4* xt4 = x_lds + t * (D / 4);
        #pragma unroll
        for (int k4 = 0; k4 < D / 4; ++k4) {
            float4 xv = xt4[k4];
            xa  = fmaf(wih[4 * k4 + 0], xv.x, xa);
            xb2 = fmaf(wih[4 * k4 + 1], xv.y, xb2);
            xc  = fmaf(wih[4 * k4 + 2], xv.z, xc);
            xd4 = fmaf(wih[4 * k4 + 3], xv.w, xd4);
        }
        const float xd = (xa + xb2) + (xc + xd4);

        if (wave < 2) {
            rz_lds[wave * H + j] = fast_sigmoid(xd + hdot);
        }
        __syncthreads();   // r,z visible; all h-dots complete
        if (wave == 2) {
            const float r    = rz_lds[j];
            const float z    = rz_lds[H + j];
            const float hold = h_lds[j];
            const float n    = fast_tanh(xd + r * (hdot + bias_hh));
            h_lds[j] = (1.0f - z) * n + z * hold;
        }
        __syncthreads();   // h updated before next step reads it
    }

    // ---- epilogue ----
    // forward final state
    if (wave == 0) last_lds[j] = h_lds[j];

    // backward direction: exactly ONE step from h0 = 0 on x[b][T-1][:]
    if (wave == 2) {
        const float* xT = reinterpret_cast<const float*>(x_lds) + (T - 1) * D;
        float xr = b_ih_b[j];
        float xz = b_ih_b[H + j];
        float xn = b_ih_b[2 * H + j];
        #pragma unroll
        for (int k = 0; k < D; ++k) {
            const float xv = xT[k];
            xr = fmaf(w_ih_b[(size_t)j * D + k],           xv, xr);
            xz = fmaf(w_ih_b[(size_t)(H + j) * D + k],     xv, xz);
            xn = fmaf(w_ih_b[(size_t)(2 * H + j) * D + k], xv, xn);
        }
        const float r = fast_sigmoid(xr + b_hh_b[j]);
        const float z = fast_sigmoid(xz + b_hh_b[H + j]);
        const float n = fast_tanh(xn + r * b_hh_b[2 * H + j]);
        last_lds[H + j] = (1.0f - z) * n;   // z*h0 = 0
    }
    __syncthreads();

    // head: h1 = leaky(fc1_w @ last + fc1_b); out = fc2_w @ h1 + fc2_b
    if (wave == 0) {
        float acc = fc1_b[j];
        const float* w1 = fc1_w + (size_t)j * (2 * H);
        #pragma unroll 8
        for (int c = 0; c < 2 * H; ++c) acc = fmaf(w1[c], last_lds[c], acc);
        acc = (acc >= 0.0f) ? acc : 0.2f * acc;
        float red = acc * fc2_w[j];
        #pragma unroll
        for (int off = 32; off > 0; off >>= 1)
            red += __shfl_down(red, off);
        if (j == 0) out[b] = red + fc2_b[0];
    }
}

extern "C" void kernel_launch(void* const* d_in, const int* in_sizes, int n_in,
                              void* d_out, int out_size, void* d_ws, size_t ws_size,
                              hipStream_t stream) {
    const float* x      = (const float*)d_in[0];
    const float* w_ih_f = (const float*)d_in[1];
    const float* w_hh_f = (const float*)d_in[2];
    const float* b_ih_f = (const float*)d_in[3];
    const float* b_hh_f = (const float*)d_in[4];
    const float* w_ih_b = (const float*)d_in[5];
    // d_in[6] = w_hh_b: unused (backward direction runs exactly one step from h0=0)
    const float* b_ih_b = (const float*)d_in[7];
    const float* b_hh_b = (const float*)d_in[8];
    const float* fc1_w  = (const float*)d_in[9];
    const float* fc1_b  = (const float*)d_in[10];
    const float* fc2_w  = (const float*)d_in[11];
    const float* fc2_b  = (const float*)d_in[12];
    float* out = (float*)d_out;

    gru_fused_kernel<<<BATCH, G, 0, stream>>>(
        x, w_ih_f, w_hh_f, b_ih_f, b_hh_f,
        w_ih_b, b_ih_b, b_hh_b,
        fc1_w, fc1_b, fc2_w, fc2_b, out);
}